// Round 3
// baseline (428.523 us; speedup 1.0000x reference)
//
#include <hip/hip_runtime.h>
#include <hip/hip_bf16.h>

// pooled[s] = sum_k ( S[s,k,:] @ W[k] ) + sum_k count[s,k]*b[k]
// S[s,k,:] = sum of atom rows in segment s with degree k.
//
// Pipeline (5 dispatches + 1 small memset):
//   memset       : zero hist (B*K u32)
//   k_hist       : histogram of keys (s*K + deg)
//   k_scan_wconv : blocks 0..K-1 convert W->bf16 transposed; block K scans
//                  hist -> bin starts (single 1024-thr block)
//   k_scatter    : counting-sort; atomicAdd on bin[] itself (starts -> ends)
//   k_phaseA     : one 128-thr half-block PER BIN: gather rows, sum -> S bf16
//   k_phaseB     : MFMA GEMM out = S @ Wb + (count . bias), plain stores

typedef short bf16x8 __attribute__((ext_vector_type(8)));
typedef float f32x4  __attribute__((ext_vector_type(4)));

__device__ __forceinline__ unsigned short f2bf(float f) {
    unsigned int u = __builtin_bit_cast(unsigned int, f);
    u += 0x7fffu + ((u >> 16) & 1u);
    return (unsigned short)(u >> 16);
}

__device__ __forceinline__ int deg_of(int i, const int* __restrict__ ds, int K) {
    int k = 0, end = 0;
    for (int kk = 0; kk < K; ++kk) { end += ds[2 * kk + 1]; k += (i >= end) ? 1 : 0; }
    return k;
}

__global__ __launch_bounds__(256) void k_hist(
    const int* __restrict__ mem, const int* __restrict__ ds,
    unsigned* __restrict__ hist, int N, int K)
{
    int i = blockIdx.x * 256 + threadIdx.x;
    if (i >= N) return;
    int key = mem[i] * K + deg_of(i, ds, K);
    atomicAdd(&hist[key], 1u);
}

// blocks [0,K): W[k][f][c] f32 -> Wb[k][c][f] bf16.  block K: exclusive scan.
__global__ __launch_bounds__(1024) void k_scan_wconv(
    const unsigned* __restrict__ hist, unsigned* __restrict__ bin,
    const float* __restrict__ W, unsigned short* __restrict__ Wb,
    int B, int K)
{
    if ((int)blockIdx.x < K) {
        __shared__ unsigned short t[128 * 130];
        int k = blockIdx.x;
        const float* Wk = W + (size_t)k * 16384;
        unsigned short* Wbk = Wb + (size_t)k * 16384;
        for (int e = threadIdx.x; e < 16384; e += 1024) {
            int f = e >> 7, c = e & 127;
            t[f * 130 + c] = f2bf(Wk[e]);
        }
        __syncthreads();
        for (int e = threadIdx.x; e < 16384; e += 1024) {
            int c = e >> 7, f = e & 127;
            Wbk[e] = t[f * 130 + c];
        }
        return;
    }
    __shared__ unsigned aux[1024];
    int t = threadIdx.x;
    int CH = (B + 1023) >> 10;
    unsigned loc = 0;
    for (int j = 0; j < CH; ++j) {
        int s = t * CH + j;
        if (s < B)
            for (int k = 0; k < K; ++k) loc += hist[s * K + k];
    }
    aux[t] = loc;
    __syncthreads();
    for (int d = 1; d < 1024; d <<= 1) {            // Hillis-Steele inclusive
        unsigned v = (t >= d) ? aux[t - d] : 0u;
        __syncthreads();
        aux[t] += v;
        __syncthreads();
    }
    unsigned run = (t > 0) ? aux[t - 1] : 0u;       // exclusive base
    for (int j = 0; j < CH; ++j) {
        int s = t * CH + j;
        if (s < B) {
            for (int k = 0; k < K; ++k) { bin[s * K + k] = run; run += hist[s * K + k]; }
        }
    }
}

// atomicAdd on bin[] itself: returns absolute slot; afterwards bin[key] = end.
__global__ __launch_bounds__(256) void k_scatter(
    const int* __restrict__ mem, const int* __restrict__ ds,
    unsigned* __restrict__ bin, unsigned* __restrict__ idx, int N, int K)
{
    int i = blockIdx.x * 256 + threadIdx.x;
    if (i >= N) return;
    int key = mem[i] * K + deg_of(i, ds, K);
    unsigned p = atomicAdd(&bin[key], 1u);
    idx[p] = (unsigned)i;
}

// One (s,k) bin per 128-thread half-block. binend convention:
// start(bin) = (bin==0) ? 0 : binend[bin-1]; end(bin) = binend[bin].
__global__ __launch_bounds__(256) void k_phaseA(
    const float* __restrict__ atoms,
    const unsigned* __restrict__ binend,
    const unsigned* __restrict__ idx,
    unsigned short* __restrict__ S, int KB)
{
    int bin = blockIdx.x * 2 + (threadIdx.x >> 7);
    int f   = threadIdx.x & 127;
    if (bin >= KB) return;
    unsigned st = (bin == 0) ? 0u : binend[bin - 1];
    unsigned en = binend[bin];
    float a0 = 0.f, a1 = 0.f, a2 = 0.f, a3 = 0.f;
    float b0 = 0.f, b1 = 0.f, b2 = 0.f, b3 = 0.f;
    unsigned j = st;
    for (; j + 8 <= en; j += 8) {                   // 8-deep MLP
        unsigned r0 = idx[j+0], r1 = idx[j+1], r2 = idx[j+2], r3 = idx[j+3];
        unsigned r4 = idx[j+4], r5 = idx[j+5], r6 = idx[j+6], r7 = idx[j+7];
        a0 += atoms[(size_t)r0 * 128 + f]; a1 += atoms[(size_t)r1 * 128 + f];
        a2 += atoms[(size_t)r2 * 128 + f]; a3 += atoms[(size_t)r3 * 128 + f];
        b0 += atoms[(size_t)r4 * 128 + f]; b1 += atoms[(size_t)r5 * 128 + f];
        b2 += atoms[(size_t)r6 * 128 + f]; b3 += atoms[(size_t)r7 * 128 + f];
    }
    if (j + 4 <= en) {                              // 4-deep step
        unsigned r0 = idx[j+0], r1 = idx[j+1], r2 = idx[j+2], r3 = idx[j+3];
        a0 += atoms[(size_t)r0 * 128 + f]; a1 += atoms[(size_t)r1 * 128 + f];
        a2 += atoms[(size_t)r2 * 128 + f]; a3 += atoms[(size_t)r3 * 128 + f];
        j += 4;
    }
    unsigned rem = en - j;                          // 0..3, wave-uniform
    if (rem > 0) b0 += atoms[(size_t)idx[j+0] * 128 + f];
    if (rem > 1) b1 += atoms[(size_t)idx[j+1] * 128 + f];
    if (rem > 2) b2 += atoms[(size_t)idx[j+2] * 128 + f];
    float acc = ((a0 + a1) + (a2 + a3)) + ((b0 + b1) + (b2 + b3));
    S[(size_t)bin * 128 + f] = f2bf(acc);
}

// One wave per (16 segments x 32 cols); K-chain = K*128. Bias folded in via
// per-row counts from binend diffs. No atomics, plain stores.
__global__ __launch_bounds__(64) void k_phaseB(
    const unsigned short* __restrict__ S,   // [B][K*128] bf16
    const unsigned short* __restrict__ Wb,  // [K][128][128] bf16 ([k][col][f])
    const unsigned* __restrict__ binend,    // [B*K]
    const float* __restrict__ bias,         // [K][128]
    float* __restrict__ out,                // [B][128]
    int K)
{
    int bx   = blockIdx.x;
    int s0   = (bx >> 2) * 16;
    int c0   = (bx & 3) * 32;
    int lane = threadIdx.x;
    int quad = lane >> 4, cb = lane & 15;

    const int KD = K * 128;
    f32x4 acc0 = (f32x4){0.f, 0.f, 0.f, 0.f};
    f32x4 acc1 = (f32x4){0.f, 0.f, 0.f, 0.f};

    const unsigned short* Arow = S  + (size_t)(s0 + cb) * KD + quad * 8;
    const unsigned short* B0   = Wb + (size_t)(c0 + cb)      * 128 + quad * 8;
    const unsigned short* B1   = Wb + (size_t)(c0 + 16 + cb) * 128 + quad * 8;

    #pragma unroll 1
    for (int kk = 0; kk < K; ++kk) {
        #pragma unroll
        for (int k0 = 0; k0 < 128; k0 += 32) {
            bf16x8 a  = *reinterpret_cast<const bf16x8*>(Arow + kk * 128 + k0);
            bf16x8 b0 = *reinterpret_cast<const bf16x8*>(B0 + (size_t)kk * 16384 + k0);
            bf16x8 b1 = *reinterpret_cast<const bf16x8*>(B1 + (size_t)kk * 16384 + k0);
            acc0 = __builtin_amdgcn_mfma_f32_16x16x32_bf16(a, b0, acc0, 0, 0, 0);
            acc1 = __builtin_amdgcn_mfma_f32_16x16x32_bf16(a, b1, acc1, 0, 0, 0);
        }
    }
    #pragma unroll
    for (int reg = 0; reg < 4; ++reg) {
        int s = s0 + quad * 4 + reg;
        unsigned prev = (s == 0) ? 0u : binend[(size_t)s * K - 1];
        float b0s = 0.f, b1s = 0.f;
        for (int k = 0; k < K; ++k) {
            unsigned e = binend[(size_t)s * K + k];
            float cnt = (float)(e - prev);
            prev = e;
            b0s += cnt * bias[k * 128 + c0 + cb];
            b1s += cnt * bias[k * 128 + c0 + 16 + cb];
        }
        out[(size_t)s * 128 + c0 + cb]      = acc0[reg] + b0s;
        out[(size_t)s * 128 + c0 + 16 + cb] = acc1[reg] + b1s;
    }
}

// ---------------- fallback (round-1 fused kernel) if ws too small ----------
#define TM 64
#define LDA 136
#define LDW 136
__global__ __launch_bounds__(256, 2) void degree_affine_pool(
    const float* __restrict__ atoms, const float* __restrict__ W,
    const float* __restrict__ bias, const int* __restrict__ deg_slice,
    const int* __restrict__ membership, float* __restrict__ out, int K)
{
    __shared__ unsigned short Alds[TM * LDA];
    __shared__ unsigned short Wlds[128 * LDW];
    const int bid = blockIdx.x, tid = threadIdx.x;
    int k = -1, tile = 0, acc_t = 0;
    for (int kk = 0; kk < K; ++kk) {
        int c = deg_slice[2 * kk + 1];
        int nt = (c + TM - 1) >> 6;
        if (k < 0 && bid < acc_t + nt) { k = kk; tile = bid - acc_t; }
        acc_t += nt;
    }
    if (k < 0) return;
    const int start = deg_slice[2 * k], cnt = deg_slice[2 * k + 1];
    const int row0 = start + tile * TM;
    const int rows_valid = min(TM, cnt - tile * TM);
    for (int e = tid; e < TM * 32; e += 256) {
        int r = e >> 5, f4 = e & 31;
        float4 v = make_float4(0.f, 0.f, 0.f, 0.f);
        if (r < rows_valid)
            v = *reinterpret_cast<const float4*>(atoms + (size_t)(row0 + r) * 128 + f4 * 4);
        unsigned lo = (unsigned)f2bf(v.x) | ((unsigned)f2bf(v.y) << 16);
        unsigned hi = (unsigned)f2bf(v.z) | ((unsigned)f2bf(v.w) << 16);
        *reinterpret_cast<uint2*>(&Alds[r * LDA + f4 * 4]) = make_uint2(lo, hi);
    }
    const float* Wk = W + (size_t)k * 16384;
    for (int e = tid; e < 8192; e += 256) {
        int c = e & 127, f2 = e >> 7;
        unsigned p = (unsigned)f2bf(Wk[(2 * f2) * 128 + c]) |
                     ((unsigned)f2bf(Wk[(2 * f2 + 1) * 128 + c]) << 16);
        *reinterpret_cast<unsigned*>(&Wlds[c * LDW + 2 * f2]) = p;
    }
    __syncthreads();
    const int wave = tid >> 6, lane = tid & 63, quad = lane >> 4, cb = lane & 15;
    f32x4 acc[8];
    #pragma unroll
    for (int ct = 0; ct < 8; ++ct) acc[ct] = (f32x4){0.f, 0.f, 0.f, 0.f};
    #pragma unroll
    for (int k0 = 0; k0 < 128; k0 += 32) {
        bf16x8 af = *reinterpret_cast<const bf16x8*>(&Alds[(wave * 16 + cb) * LDA + k0 + quad * 8]);
        #pragma unroll
        for (int ct = 0; ct < 8; ++ct) {
            bf16x8 bf = *reinterpret_cast<const bf16x8*>(&Wlds[(ct * 16 + cb) * LDW + k0 + quad * 8]);
            acc[ct] = __builtin_amdgcn_mfma_f32_16x16x32_bf16(af, bf, acc[ct], 0, 0, 0);
        }
    }
    int segs[4]; bool valid[4];
    #pragma unroll
    for (int reg = 0; reg < 4; ++reg) {
        int rl = wave * 16 + quad * 4 + reg;
        valid[reg] = (rl < rows_valid);
        segs[reg] = valid[reg] ? membership[row0 + rl] : 0;
    }
    const float* bk = bias + k * 128;
    #pragma unroll
    for (int ct = 0; ct < 8; ++ct) {
        int col = ct * 16 + cb;
        float bv = bk[col];
        #pragma unroll
        for (int reg = 0; reg < 4; ++reg)
            if (valid[reg])
                __hip_atomic_fetch_add(out + (size_t)segs[reg] * 128 + col,
                                       acc[ct][reg] + bv, __ATOMIC_RELAXED,
                                       __HIP_MEMORY_SCOPE_AGENT);
    }
}
// ---------------------------------------------------------------------------

static inline size_t aln(size_t x) { return (x + 255) & ~(size_t)255; }

extern "C" void kernel_launch(void* const* d_in, const int* in_sizes, int n_in,
                              void* d_out, int out_size, void* d_ws, size_t ws_size,
                              hipStream_t stream) {
    const float* atoms = (const float*)d_in[0];
    const float* W     = (const float*)d_in[1];
    const float* bias  = (const float*)d_in[2];
    const int*   deg   = (const int*)d_in[3];
    const int*   mem   = (const int*)d_in[4];
    float*       out   = (float*)d_out;

    const int K = in_sizes[3] / 2;       // 11
    const int N = in_sizes[0] / 128;     // 393216
    const int B = out_size / 128;        // 4096
    const int KB = B * K;                // 45056 bins

    // workspace plan
    size_t oWb   = 0;                         size_t sWb   = (size_t)K * 16384 * 2;
    size_t oHist = aln(oWb + sWb);            size_t sHist = (size_t)KB * 4;
    size_t oBin  = aln(oHist + sHist);        size_t sBin  = (size_t)KB * 4;
    size_t oIdx  = aln(oBin + sBin);          size_t sIdx  = (size_t)N * 4;
    size_t oS    = aln(oIdx + sIdx);          size_t sS    = (size_t)KB * 128 * 2;
    size_t total = oS + sS;                   // ~13.7 MB

    if (ws_size < total || (B & 15) != 0) {
        (void)hipMemsetAsync(d_out, 0, (size_t)out_size * sizeof(float), stream);
        const int blocks = (N + TM - 1) / TM + K;
        degree_affine_pool<<<blocks, 256, 0, stream>>>(atoms, W, bias, deg, mem, out, K);
        return;
    }

    char* ws = (char*)d_ws;
    unsigned short* Wb   = (unsigned short*)(ws + oWb);
    unsigned*       hist = (unsigned*)(ws + oHist);
    unsigned*       bin  = (unsigned*)(ws + oBin);
    unsigned*       idx  = (unsigned*)(ws + oIdx);
    unsigned short* S    = (unsigned short*)(ws + oS);

    (void)hipMemsetAsync(hist, 0, sHist, stream);

    const int nb = (N + 255) / 256;
    k_hist      <<<nb, 256, 0, stream>>>(mem, deg, hist, N, K);
    k_scan_wconv<<<K + 1, 1024, 0, stream>>>(hist, bin, W, Wb, B, K);
    k_scatter   <<<nb, 256, 0, stream>>>(mem, deg, bin, idx, N, K);
    k_phaseA    <<<(KB + 1) / 2, 256, 0, stream>>>(atoms, bin, idx, S, KB);
    k_phaseB    <<<(B / 16) * 4, 64, 0, stream>>>(S, Wb, bin, bias, out, K);
}

// Round 4
// 347.734 us; speedup vs baseline: 1.2323x; 1.2323x over previous
//
#include <hip/hip_runtime.h>
#include <hip/hip_bf16.h>

// pooled[s] = sum_k ( S[s,k,:] @ W[k] ) + sum_k count[s,k]*b[k]
// S[s,k,:] = sum of atom rows in segment s with degree k.
//
// Pipeline (4 dispatches):
//   memset       : zero cnt (B*K u32, 180 KB)
//   k_fill_wconv : bucket-fill slots[key*CAP+p]=i (one pass, no sort);
//                  last K blocks convert W -> bf16 transposed
//   k_phaseA     : one WAVE per (s,k) bin: gather rows float4-wide, sum,
//                  cross-parity shfl reduce -> S bf16
//   k_phaseB     : MFMA GEMM out = S @ Wb + (cnt . bias), plain stores

#define CAP 64   // max atoms per (segment,degree) bin; Poisson(8.7) -> safe

typedef short bf16x8 __attribute__((ext_vector_type(8)));
typedef float f32x4  __attribute__((ext_vector_type(4)));

__device__ __forceinline__ unsigned short f2bf(float f) {
    unsigned int u = __builtin_bit_cast(unsigned int, f);
    u += 0x7fffu + ((u >> 16) & 1u);
    return (unsigned short)(u >> 16);
}

__device__ __forceinline__ int deg_of(int i, const int* __restrict__ ds, int K) {
    int k = 0, end = 0;
    for (int kk = 0; kk < K; ++kk) { end += ds[2 * kk + 1]; k += (i >= end) ? 1 : 0; }
    return k;
}

// blocks [0,nb): bucket fill.  blocks [nb,nb+K): W[k][f][c] f32 -> Wb[k][c][f] bf16.
__global__ __launch_bounds__(256) void k_fill_wconv(
    const int* __restrict__ mem, const int* __restrict__ ds,
    const float* __restrict__ W,
    unsigned* __restrict__ cnt, unsigned* __restrict__ slots,
    unsigned short* __restrict__ Wb, int N, int K, int nb)
{
    int bx = blockIdx.x;
    if (bx >= nb) {
        __shared__ unsigned short t[128 * 130];
        int k = bx - nb;
        const float* Wk = W + (size_t)k * 16384;
        unsigned short* Wbk = Wb + (size_t)k * 16384;
        for (int e = threadIdx.x; e < 16384; e += 256) {
            int f = e >> 7, c = e & 127;
            t[f * 130 + c] = f2bf(Wk[e]);
        }
        __syncthreads();
        for (int e = threadIdx.x; e < 16384; e += 256) {
            int c = e >> 7, f = e & 127;
            Wbk[e] = t[f * 130 + c];
        }
        return;
    }
    int i = bx * 256 + threadIdx.x;
    if (i >= N) return;
    int key = mem[i] * K + deg_of(i, ds, K);
    unsigned p = atomicAdd(&cnt[key], 1u);
    if (p < CAP) slots[(size_t)key * CAP + p] = (unsigned)i;
}

__device__ __forceinline__ float4 f4add(float4 a, float4 b) {
    return make_float4(a.x + b.x, a.y + b.y, a.z + b.z, a.w + b.w);
}

// One WAVE per bin. Lanes: rpar = lane>>5 (row parity), f4 = lane&31
// (float4 within the 128-float row). Each row read = one contiguous 512 B.
__global__ __launch_bounds__(256) void k_phaseA(
    const float* __restrict__ atoms,
    const unsigned* __restrict__ cnt,
    const unsigned* __restrict__ slots,
    unsigned short* __restrict__ S, int KB)
{
    int bin = blockIdx.x * 4 + (threadIdx.x >> 6);
    if (bin >= KB) return;
    int lane = threadIdx.x & 63;
    int rpar = lane >> 5;
    int f4   = lane & 31;
    int n = (int)cnt[bin];
    if (n > CAP) n = CAP;
    const unsigned* sl = slots + (size_t)bin * CAP;

    float4 A0 = make_float4(0.f, 0.f, 0.f, 0.f);
    float4 A1 = A0, A2 = A0, A3 = A0;
    int j = rpar;
    for (; j + 6 < n; j += 8) {                 // 8 rows in flight per wave
        unsigned r0 = sl[j], r1 = sl[j + 2], r2 = sl[j + 4], r3 = sl[j + 6];
        float4 v0 = *reinterpret_cast<const float4*>(atoms + (size_t)r0 * 128 + f4 * 4);
        float4 v1 = *reinterpret_cast<const float4*>(atoms + (size_t)r1 * 128 + f4 * 4);
        float4 v2 = *reinterpret_cast<const float4*>(atoms + (size_t)r2 * 128 + f4 * 4);
        float4 v3 = *reinterpret_cast<const float4*>(atoms + (size_t)r3 * 128 + f4 * 4);
        A0 = f4add(A0, v0); A1 = f4add(A1, v1);
        A2 = f4add(A2, v2); A3 = f4add(A3, v3);
    }
    for (; j < n; j += 2) {
        float4 v = *reinterpret_cast<const float4*>(atoms + (size_t)sl[j] * 128 + f4 * 4);
        A0 = f4add(A0, v);
    }
    float4 Sm = f4add(f4add(A0, A1), f4add(A2, A3));
    Sm.x += __shfl_xor(Sm.x, 32, 64);           // merge row parities
    Sm.y += __shfl_xor(Sm.y, 32, 64);
    Sm.z += __shfl_xor(Sm.z, 32, 64);
    Sm.w += __shfl_xor(Sm.w, 32, 64);
    if (rpar == 0) {
        unsigned lo = (unsigned)f2bf(Sm.x) | ((unsigned)f2bf(Sm.y) << 16);
        unsigned hi = (unsigned)f2bf(Sm.z) | ((unsigned)f2bf(Sm.w) << 16);
        *reinterpret_cast<uint2*>(S + (size_t)bin * 128 + f4 * 4) = make_uint2(lo, hi);
    }
}

// One wave per (16 segments x 32 cols); K-chain = K*128. Bias from cnt.
__global__ __launch_bounds__(64) void k_phaseB(
    const unsigned short* __restrict__ S,   // [B][K*128] bf16
    const unsigned short* __restrict__ Wb,  // [K][128][128] bf16 ([k][col][f])
    const unsigned* __restrict__ cnt,       // [B*K]
    const float* __restrict__ bias,         // [K][128]
    float* __restrict__ out,                // [B][128]
    int K)
{
    int bx   = blockIdx.x;
    int s0   = (bx >> 2) * 16;
    int c0   = (bx & 3) * 32;
    int lane = threadIdx.x;
    int quad = lane >> 4, cb = lane & 15;

    const int KD = K * 128;
    f32x4 acc0 = (f32x4){0.f, 0.f, 0.f, 0.f};
    f32x4 acc1 = (f32x4){0.f, 0.f, 0.f, 0.f};

    const unsigned short* Arow = S  + (size_t)(s0 + cb) * KD + quad * 8;
    const unsigned short* B0   = Wb + (size_t)(c0 + cb)      * 128 + quad * 8;
    const unsigned short* B1   = Wb + (size_t)(c0 + 16 + cb) * 128 + quad * 8;

    #pragma unroll 1
    for (int kk = 0; kk < K; ++kk) {
        #pragma unroll
        for (int k0 = 0; k0 < 128; k0 += 32) {
            bf16x8 a  = *reinterpret_cast<const bf16x8*>(Arow + kk * 128 + k0);
            bf16x8 b0 = *reinterpret_cast<const bf16x8*>(B0 + (size_t)kk * 16384 + k0);
            bf16x8 b1 = *reinterpret_cast<const bf16x8*>(B1 + (size_t)kk * 16384 + k0);
            acc0 = __builtin_amdgcn_mfma_f32_16x16x32_bf16(a, b0, acc0, 0, 0, 0);
            acc1 = __builtin_amdgcn_mfma_f32_16x16x32_bf16(a, b1, acc1, 0, 0, 0);
        }
    }
    #pragma unroll
    for (int reg = 0; reg < 4; ++reg) {
        int s = s0 + quad * 4 + reg;
        float b0s = 0.f, b1s = 0.f;
        for (int k = 0; k < K; ++k) {
            float c = (float)cnt[(size_t)s * K + k];   // true count (bias exact)
            b0s += c * bias[k * 128 + c0 + cb];
            b1s += c * bias[k * 128 + c0 + 16 + cb];
        }
        out[(size_t)s * 128 + c0 + cb]      = acc0[reg] + b0s;
        out[(size_t)s * 128 + c0 + 16 + cb] = acc1[reg] + b1s;
    }
}

// ---------------- fallback (round-1 fused kernel) if ws too small ----------
#define TM 64
#define LDA 136
#define LDW 136
__global__ __launch_bounds__(256, 2) void degree_affine_pool(
    const float* __restrict__ atoms, const float* __restrict__ W,
    const float* __restrict__ bias, const int* __restrict__ deg_slice,
    const int* __restrict__ membership, float* __restrict__ out, int K)
{
    __shared__ unsigned short Alds[TM * LDA];
    __shared__ unsigned short Wlds[128 * LDW];
    const int bid = blockIdx.x, tid = threadIdx.x;
    int k = -1, tile = 0, acc_t = 0;
    for (int kk = 0; kk < K; ++kk) {
        int c = deg_slice[2 * kk + 1];
        int nt = (c + TM - 1) >> 6;
        if (k < 0 && bid < acc_t + nt) { k = kk; tile = bid - acc_t; }
        acc_t += nt;
    }
    if (k < 0) return;
    const int start = deg_slice[2 * k], cnt = deg_slice[2 * k + 1];
    const int row0 = start + tile * TM;
    const int rows_valid = min(TM, cnt - tile * TM);
    for (int e = tid; e < TM * 32; e += 256) {
        int r = e >> 5, f4 = e & 31;
        float4 v = make_float4(0.f, 0.f, 0.f, 0.f);
        if (r < rows_valid)
            v = *reinterpret_cast<const float4*>(atoms + (size_t)(row0 + r) * 128 + f4 * 4);
        unsigned lo = (unsigned)f2bf(v.x) | ((unsigned)f2bf(v.y) << 16);
        unsigned hi = (unsigned)f2bf(v.z) | ((unsigned)f2bf(v.w) << 16);
        *reinterpret_cast<uint2*>(&Alds[r * LDA + f4 * 4]) = make_uint2(lo, hi);
    }
    const float* Wk = W + (size_t)k * 16384;
    for (int e = tid; e < 8192; e += 256) {
        int c = e & 127, f2 = e >> 7;
        unsigned p = (unsigned)f2bf(Wk[(2 * f2) * 128 + c]) |
                     ((unsigned)f2bf(Wk[(2 * f2 + 1) * 128 + c]) << 16);
        *reinterpret_cast<unsigned*>(&Wlds[c * LDW + 2 * f2]) = p;
    }
    __syncthreads();
    const int wave = tid >> 6, lane = tid & 63, quad = lane >> 4, cb = lane & 15;
    f32x4 acc[8];
    #pragma unroll
    for (int ct = 0; ct < 8; ++ct) acc[ct] = (f32x4){0.f, 0.f, 0.f, 0.f};
    #pragma unroll
    for (int k0 = 0; k0 < 128; k0 += 32) {
        bf16x8 af = *reinterpret_cast<const bf16x8*>(&Alds[(wave * 16 + cb) * LDA + k0 + quad * 8]);
        #pragma unroll
        for (int ct = 0; ct < 8; ++ct) {
            bf16x8 bf = *reinterpret_cast<const bf16x8*>(&Wlds[(ct * 16 + cb) * LDW + k0 + quad * 8]);
            acc[ct] = __builtin_amdgcn_mfma_f32_16x16x32_bf16(af, bf, acc[ct], 0, 0, 0);
        }
    }
    int segs[4]; bool valid[4];
    #pragma unroll
    for (int reg = 0; reg < 4; ++reg) {
        int rl = wave * 16 + quad * 4 + reg;
        valid[reg] = (rl < rows_valid);
        segs[reg] = valid[reg] ? membership[row0 + rl] : 0;
    }
    const float* bk = bias + k * 128;
    #pragma unroll
    for (int ct = 0; ct < 8; ++ct) {
        int col = ct * 16 + cb;
        float bv = bk[col];
        #pragma unroll
        for (int reg = 0; reg < 4; ++reg)
            if (valid[reg])
                __hip_atomic_fetch_add(out + (size_t)segs[reg] * 128 + col,
                                       acc[ct][reg] + bv, __ATOMIC_RELAXED,
                                       __HIP_MEMORY_SCOPE_AGENT);
    }
}
// ---------------------------------------------------------------------------

static inline size_t aln(size_t x) { return (x + 255) & ~(size_t)255; }

extern "C" void kernel_launch(void* const* d_in, const int* in_sizes, int n_in,
                              void* d_out, int out_size, void* d_ws, size_t ws_size,
                              hipStream_t stream) {
    const float* atoms = (const float*)d_in[0];
    const float* W     = (const float*)d_in[1];
    const float* bias  = (const float*)d_in[2];
    const int*   deg   = (const int*)d_in[3];
    const int*   mem   = (const int*)d_in[4];
    float*       out   = (float*)d_out;

    const int K  = in_sizes[3] / 2;      // 11
    const int N  = in_sizes[0] / 128;    // 393216
    const int B  = out_size / 128;       // 4096
    const int KB = B * K;                // 45056 bins

    // workspace plan (~23.6 MB)
    size_t oWb   = 0;                       size_t sWb   = (size_t)K * 16384 * 2;
    size_t oCnt  = aln(oWb + sWb);          size_t sCnt  = (size_t)KB * 4;
    size_t oSlot = aln(oCnt + sCnt);        size_t sSlot = (size_t)KB * CAP * 4;
    size_t oS    = aln(oSlot + sSlot);      size_t sS    = (size_t)KB * 128 * 2;
    size_t total = oS + sS;

    if (ws_size < total || (B & 15) != 0) {
        (void)hipMemsetAsync(d_out, 0, (size_t)out_size * sizeof(float), stream);
        const int blocks = (N + TM - 1) / TM + K;
        degree_affine_pool<<<blocks, 256, 0, stream>>>(atoms, W, bias, deg, mem, out, K);
        return;
    }

    char* ws = (char*)d_ws;
    unsigned short* Wb    = (unsigned short*)(ws + oWb);
    unsigned*       cnt   = (unsigned*)(ws + oCnt);
    unsigned*       slots = (unsigned*)(ws + oSlot);
    unsigned short* S     = (unsigned short*)(ws + oS);

    (void)hipMemsetAsync(cnt, 0, sCnt, stream);

    const int nb = (N + 255) / 256;
    k_fill_wconv<<<nb + K, 256, 0, stream>>>(mem, deg, W, cnt, slots, Wb, N, K, nb);
    k_phaseA    <<<(KB + 3) / 4, 256, 0, stream>>>(atoms, cnt, slots, S, KB);
    k_phaseB    <<<(B / 16) * 4, 64, 0, stream>>>(S, Wb, cnt, bias, out, K);
}